// Round 12
// baseline (62.756 us; speedup 1.0000x reference)
//
#include <hip/hip_runtime.h>

// GaussianKernel: out[row, o] = exp(-(||x_row||^2 - 2 x_row.w_o + ||w_o||^2)) + b[o]
// x: 262144 rows x 32 fp32; w: [32,128]; b: [128]; out fp32.
//
// Round-10: MFMA path hit 33.7 us (from 66). Round-11 failed to compile:
// __builtin_nontemporal_load needs ext-vector types, not HIP_vector_type.
// Fix: f32x4v ext_vector alias for the x loads. Levers unchanged: (1) 2-deep
// prefetch of next row-tile's A fragments; (2) non-temporal loads/stores for
// the stream-once x and out. Structure + m89-verified C layout unchanged.

typedef short bf16x8 __attribute__((ext_vector_type(8)));
typedef float f32x4  __attribute__((ext_vector_type(4)));

constexpr int C_DIM   = 32;
constexpr int OUT_DIM = 128;
constexpr int ROWTILES_PER_BLOCK = 4;    // 4 x 32 rows = 128 rows per block
constexpr float LOG2E = 1.4426950408889634f;

__device__ __forceinline__ short f2bf(float f) {   // RNE fp32->bf16 (no NaN in data)
    unsigned u = __float_as_uint(f);
    u += 0x7fffu + ((u >> 16) & 1u);
    return (short)(u >> 16);
}

__global__ __launch_bounds__(256, 4)
void gaussian_mfma_kernel(const float* __restrict__ x,
                          const float* __restrict__ w,
                          const float* __restrict__ bias,
                          float* __restrict__ out,
                          int total_rows)
{
    const int lane = threadIdx.x & 63;
    const int wid  = threadIdx.x >> 6;
    const int colHalf = wid & 1;        // wave covers cols [colHalf*64, +64)
    const int rowSub  = wid >> 1;       // which 16-row sub-tile of the 32-row tile
    const int cbase = colHalf * 64;
    const int kg = lane >> 4;           // k-group 0..3 (8 k each)
    const int lr = lane & 15;           // row (A) / col (B,C) within 16-tile

    // --- B fragments for 4 col-tiles + fp32 wsq/bias: once per block ---
    bf16x8 bfrag[4];
    float  wsqv[4], bv[4];
#pragma unroll
    for (int t = 0; t < 4; ++t) {
        const int col = cbase + t * 16 + lr;
        float tmp[8];
        float p = 0.f;
#pragma unroll
        for (int j = 0; j < 8; ++j) {
            const float v = w[(kg * 8 + j) * OUT_DIM + col];  // 16KB, L2-hot
            tmp[j] = v;
            p = fmaf(v, v, p);
        }
        p += __shfl_xor(p, 16);          // combine the 4 k-groups -> full ||w_col||^2
        p += __shfl_xor(p, 32);
        wsqv[t] = p;
        bv[t]   = bias[col];
#pragma unroll
        for (int j = 0; j < 8; ++j) bfrag[t][j] = f2bf(tmp[j]);
    }

    const long rbase = (long)blockIdx.x * (32 * ROWTILES_PER_BLOCK)
                     + rowSub * 16 + lr;

    // Prologue: load row-tile 0's A fragment (stream-once -> non-temporal).
    const f32x4* xp0 = reinterpret_cast<const f32x4*>(x + rbase * C_DIM + kg * 8);
    f32x4 a0 = __builtin_nontemporal_load(xp0);
    f32x4 a1 = __builtin_nontemporal_load(xp0 + 1);

#pragma unroll
    for (int rt = 0; rt < ROWTILES_PER_BLOCK; ++rt) {
        const long row0 = (long)blockIdx.x * (32 * ROWTILES_PER_BLOCK) + rt * 32
                        + rowSub * 16;

        // Prefetch next row-tile's A before this tile's compute/epilogue.
        f32x4 na0, na1;
        if (rt + 1 < ROWTILES_PER_BLOCK) {
            const f32x4* xp = reinterpret_cast<const f32x4*>(
                x + (rbase + (rt + 1) * 32) * C_DIM + kg * 8);
            na0 = __builtin_nontemporal_load(xp);
            na1 = __builtin_nontemporal_load(xp + 1);
        }

        // fp32 xsq: per-lane partial over its 8 elems, combine across k-groups.
        float p = 0.f;
#pragma unroll
        for (int j = 0; j < 4; ++j) {
            p = fmaf(a0[j], a0[j], p);
            p = fmaf(a1[j], a1[j], p);
        }
        p += __shfl_xor(p, 16);
        p += __shfl_xor(p, 32);          // all lanes: xsq[row0 + lr]

        bf16x8 afrag;
#pragma unroll
        for (int j = 0; j < 4; ++j) {
            afrag[j]     = f2bf(a0[j]);
            afrag[j + 4] = f2bf(a1[j]);
        }

        // xsq values for the 4 C rows this lane writes: row = kg*4 + reg.
        float xq[4];
#pragma unroll
        for (int reg = 0; reg < 4; ++reg)
            xq[reg] = __shfl(p, kg * 4 + reg);   // bpermute; value replicated

        // 4 MFMAs: one per 16-col tile, each with full K=32.
        f32x4 acc[4];
#pragma unroll
        for (int t = 0; t < 4; ++t) {
            acc[t] = (f32x4){0.f, 0.f, 0.f, 0.f};
            acc[t] = __builtin_amdgcn_mfma_f32_16x16x32_bf16(
                         afrag, bfrag[t], acc[t], 0, 0, 0);
        }

        // Epilogue + non-temporal stores. C layout (m89): col=lane&15,
        // row=(lane>>4)*4+reg -> 16 lanes cover a 64-B segment per (t,reg).
#pragma unroll
        for (int t = 0; t < 4; ++t) {
#pragma unroll
            for (int reg = 0; reg < 4; ++reg) {
                const float d   = acc[t][reg];
                const float arg = (fmaf(2.f, d, -xq[reg]) - wsqv[t]) * LOG2E;
                const float r   = exp2f(arg) + bv[t];
                __builtin_nontemporal_store(
                    r, out + (row0 + kg * 4 + reg) * OUT_DIM + cbase + t * 16 + lr);
            }
        }

        a0 = na0; a1 = na1;
    }
}

extern "C" void kernel_launch(void* const* d_in, const int* in_sizes, int n_in,
                              void* d_out, int out_size, void* d_ws, size_t ws_size,
                              hipStream_t stream) {
    const float* x = (const float*)d_in[0];
    const float* w = (const float*)d_in[1];
    const float* b = (const float*)d_in[2];
    float* out = (float*)d_out;

    const int total_rows = in_sizes[0] / C_DIM;                // 262144
    const int rows_per_block = 32 * ROWTILES_PER_BLOCK;        // 128
    const int nblocks = (total_rows + rows_per_block - 1) / rows_per_block;  // 2048

    gaussian_mfma_kernel<<<nblocks, 256, 0, stream>>>(x, w, b, out, total_rows);
}

// Round 13
// 33.073 us; speedup vs baseline: 1.8975x; 1.8975x over previous
//
#include <hip/hip_runtime.h>

// GaussianKernel: out[row, o] = exp(-(||x_row||^2 - 2 x_row.w_o + ||w_o||^2)) + b[o]
// x: 262144 rows x 32 fp32; w: [32,128]; b: [128]; out fp32.
//
// Round-12 post-mortem: nt stores broke L2 write-combining (each store instr
// writes 4x 64-B segments; nt bypasses L2 -> partial-line HBM writes) ->
// 33.7->62.8 us. Reverted all nt. This round = round-10 kernel + ONE change:
// 2-deep prefetch of the next row-tile's A fragments (regular cached loads).
// Structure + m89-verified C layout unchanged.

typedef short bf16x8 __attribute__((ext_vector_type(8)));
typedef float f32x4  __attribute__((ext_vector_type(4)));

constexpr int C_DIM   = 32;
constexpr int OUT_DIM = 128;
constexpr int ROWTILES_PER_BLOCK = 4;    // 4 x 32 rows = 128 rows per block
constexpr float LOG2E = 1.4426950408889634f;

__device__ __forceinline__ short f2bf(float f) {   // RNE fp32->bf16 (no NaN in data)
    unsigned u = __float_as_uint(f);
    u += 0x7fffu + ((u >> 16) & 1u);
    return (short)(u >> 16);
}

__global__ __launch_bounds__(256, 4)
void gaussian_mfma_kernel(const float* __restrict__ x,
                          const float* __restrict__ w,
                          const float* __restrict__ bias,
                          float* __restrict__ out,
                          int total_rows)
{
    const int lane = threadIdx.x & 63;
    const int wid  = threadIdx.x >> 6;
    const int colHalf = wid & 1;        // wave covers cols [colHalf*64, +64)
    const int rowSub  = wid >> 1;       // which 16-row sub-tile of the 32-row tile
    const int cbase = colHalf * 64;
    const int kg = lane >> 4;           // k-group 0..3 (8 k each)
    const int lr = lane & 15;           // row (A) / col (B,C) within 16-tile

    // --- B fragments for 4 col-tiles + fp32 wsq/bias: once per block ---
    bf16x8 bfrag[4];
    float  wsqv[4], bv[4];
#pragma unroll
    for (int t = 0; t < 4; ++t) {
        const int col = cbase + t * 16 + lr;
        float tmp[8];
        float p = 0.f;
#pragma unroll
        for (int j = 0; j < 8; ++j) {
            const float v = w[(kg * 8 + j) * OUT_DIM + col];  // 16KB, L2-hot
            tmp[j] = v;
            p = fmaf(v, v, p);
        }
        p += __shfl_xor(p, 16);          // combine the 4 k-groups -> full ||w_col||^2
        p += __shfl_xor(p, 32);
        wsqv[t] = p;
        bv[t]   = bias[col];
#pragma unroll
        for (int j = 0; j < 8; ++j) bfrag[t][j] = f2bf(tmp[j]);
    }

    const long rbase = (long)blockIdx.x * (32 * ROWTILES_PER_BLOCK)
                     + rowSub * 16 + lr;

    // Prologue: load row-tile 0's A fragment.
    const float4* xp0 = reinterpret_cast<const float4*>(x + rbase * C_DIM + kg * 8);
    float4 a0 = xp0[0];
    float4 a1 = xp0[1];

#pragma unroll
    for (int rt = 0; rt < ROWTILES_PER_BLOCK; ++rt) {
        const long row0 = (long)blockIdx.x * (32 * ROWTILES_PER_BLOCK) + rt * 32
                        + rowSub * 16;

        // Prefetch next row-tile's A before this tile's compute/epilogue.
        float4 na0, na1;
        if (rt + 1 < ROWTILES_PER_BLOCK) {
            const float4* xp = reinterpret_cast<const float4*>(
                x + (rbase + (rt + 1) * 32) * C_DIM + kg * 8);
            na0 = xp[0];
            na1 = xp[1];
        }

        // fp32 xsq: per-lane partial over its 8 elems, combine across k-groups.
        float p = 0.f;
        p = fmaf(a0.x, a0.x, p); p = fmaf(a0.y, a0.y, p);
        p = fmaf(a0.z, a0.z, p); p = fmaf(a0.w, a0.w, p);
        p = fmaf(a1.x, a1.x, p); p = fmaf(a1.y, a1.y, p);
        p = fmaf(a1.z, a1.z, p); p = fmaf(a1.w, a1.w, p);
        p += __shfl_xor(p, 16);
        p += __shfl_xor(p, 32);          // all lanes: xsq[row0 + lr]

        bf16x8 afrag;
        afrag[0] = f2bf(a0.x); afrag[1] = f2bf(a0.y);
        afrag[2] = f2bf(a0.z); afrag[3] = f2bf(a0.w);
        afrag[4] = f2bf(a1.x); afrag[5] = f2bf(a1.y);
        afrag[6] = f2bf(a1.z); afrag[7] = f2bf(a1.w);

        // xsq values for the 4 C rows this lane writes: row = kg*4 + reg.
        float xq[4];
#pragma unroll
        for (int reg = 0; reg < 4; ++reg)
            xq[reg] = __shfl(p, kg * 4 + reg);   // bpermute; value replicated

        // 4 MFMAs: one per 16-col tile, each with full K=32.
        f32x4 acc[4];
#pragma unroll
        for (int t = 0; t < 4; ++t) {
            acc[t] = (f32x4){0.f, 0.f, 0.f, 0.f};
            acc[t] = __builtin_amdgcn_mfma_f32_16x16x32_bf16(
                         afrag, bfrag[t], acc[t], 0, 0, 0);
        }

        // Epilogue + store. C layout (m89): col = lane&15, row = (lane>>4)*4+reg
        // -> each store instr covers 4x 64-B contiguous segments (L2-combined).
#pragma unroll
        for (int t = 0; t < 4; ++t) {
#pragma unroll
            for (int reg = 0; reg < 4; ++reg) {
                const float d   = acc[t][reg];
                const float arg = (fmaf(2.f, d, -xq[reg]) - wsqv[t]) * LOG2E;
                const float r   = exp2f(arg) + bv[t];
                out[(row0 + kg * 4 + reg) * OUT_DIM + cbase + t * 16 + lr] = r;
            }
        }

        a0 = na0; a1 = na1;
    }
}

extern "C" void kernel_launch(void* const* d_in, const int* in_sizes, int n_in,
                              void* d_out, int out_size, void* d_ws, size_t ws_size,
                              hipStream_t stream) {
    const float* x = (const float*)d_in[0];
    const float* w = (const float*)d_in[1];
    const float* b = (const float*)d_in[2];
    float* out = (float*)d_out;

    const int total_rows = in_sizes[0] / C_DIM;                // 262144
    const int rows_per_block = 32 * ROWTILES_PER_BLOCK;        // 128
    const int nblocks = (total_rows + rows_per_block - 1) / rows_per_block;  // 2048

    gaussian_mfma_kernel<<<nblocks, 256, 0, stream>>>(x, w, b, out, total_rows);
}